// Round 1
// baseline (498.649 us; speedup 1.0000x reference)
//
#include <hip/hip_runtime.h>
#include <math.h>

// Problem dims (fixed by setup_inputs)
constexpr int Bc = 64;
constexpr int Tc = 1000;
constexpr int Vc = 512;
constexpr int Uc = 256;

#define NEG_INF_F (-100000.0f)
#define NLOG2 (-0.69314718055994531f)

__device__ __forceinline__ float logadd2(float x, float y) {
    float m = fmaxf(x, y);
    float d = fminf(x, y) - m;          // <= 0, may be -inf
    return m + __logf(1.0f + __expf(d)); // expf(-inf) -> 0
}

// One HMM step for the 4 interleaved states per lane (state i = lane + 64*c).
__device__ __forceinline__ void hmm_step(float alpha[4], const float e[4],
                                         const float s[4], const bool valid[4],
                                         int lane) {
    float sh[4];
#pragma unroll
    for (int c = 0; c < 4; ++c)
        sh[c] = __shfl(alpha[c], (lane + 63) & 63, 64); // value from lane-1 (wraps)
    float nb[4];
    nb[0] = (lane == 0) ? -INFINITY : sh[0]; // state -1 does not exist
#pragma unroll
    for (int c = 1; c < 4; ++c)
        nb[c] = (lane == 0) ? sh[c - 1] : sh[c]; // lane0 chunk c needs lane63 chunk c-1
#pragma unroll
    for (int c = 0; c < 4; ++c) {
        float x = logadd2(s[c] + alpha[c], nb[c] + NLOG2);
        alpha[c] = valid[c] ? (x + e[c]) : NEG_INF_F;
    }
}

// ---------------- Phase 1: gather emissions into permuted layout ----------------
// ews[b][t][j] where j = lane*4 + c corresponds to state i = lane + 64*c.
__global__ __launch_bounds__(256) void gather_kernel(
    const float* __restrict__ lp, const float* __restrict__ lens,
    const int* __restrict__ phns, const float* __restrict__ phn_lens,
    float* __restrict__ ews) {
    const int RPB = 8;
    const int nchunk = (Tc + RPB - 1) / RPB; // 125
    int b = blockIdx.x / nchunk;
    int tc = blockIdx.x % nchunk;
    int j = threadIdx.x;           // 0..255
    int l = j >> 2, c = j & 3;
    int i = l + 64 * c;            // state index
    int Tv = (int)rintf(lens[b] * (float)Tc);
    int Uv = (int)rintf(phn_lens[b] * (float)Uc);
    int col = phns[b * Uc + i];
    if (col < 0) col = 0;
    if (col >= Vc) col = Vc - 1;
    bool iv = (i < Uv);
    const float* lpb = lp + (size_t)b * Tc * Vc;
    float* eb = ews + (size_t)b * Tc * 256;
    int t0 = tc * RPB;
    int t1 = t0 + RPB < Tc ? t0 + RPB : Tc;
    for (int t = t0; t < t1; ++t) {
        float e = NEG_INF_F;
        if (iv && t < Tv) e = lpb[(size_t)t * Vc + col];
        eb[(size_t)t * 256 + j] = e; // coalesced
    }
}

// ---------------- Phase 2: sequential scan, one wave per batch ----------------
__global__ __launch_bounds__(64) void scan_kernel(
    const float* __restrict__ ews, const float* __restrict__ lens,
    const float* __restrict__ phn_lens, float* __restrict__ out) {
    int b = blockIdx.x;
    int lane = threadIdx.x;
    int Uv = (int)rintf(phn_lens[b] * (float)Uc);

    const float4* e4 = (const float4*)(ews + (size_t)b * Tc * 256) + lane;
    // row stride in float4 units = 64

    float s[4];
    bool valid[4];
    float alpha[4];
    float4 e0 = e4[0];
    float e0a[4] = {e0.x, e0.y, e0.z, e0.w};
#pragma unroll
    for (int c = 0; c < 4; ++c) {
        int i = lane + 64 * c;
        valid[c] = (i < Uv);
        s[c] = (i == Uv - 1) ? 0.0f : NLOG2;
        alpha[c] = ((i == 0) ? 0.0f : NEG_INF_F) + e0a[c]; // pi + emiss[0]
    }

    const int PF = 8;
    float4 q[PF];
#pragma unroll
    for (int p = 0; p < PF; ++p) {
        int t = 1 + p;
        if (t > Tc - 1) t = Tc - 1;
        q[p] = e4[(size_t)t * 64];
    }

    int tb;
    for (tb = 1; tb + PF <= Tc; tb += PF) {
#pragma unroll
        for (int u = 0; u < PF; ++u) {
            int t = tb + u;
            float4 ev = q[u];
            int tn = t + PF;
            if (tn < Tc) q[u] = e4[(size_t)tn * 64]; // prefetch PF steps ahead
            float e[4] = {ev.x, ev.y, ev.z, ev.w};
            hmm_step(alpha, e, s, valid, lane);
        }
    }
    // tail (< PF steps), values already prefetched in q[0..]
#pragma unroll
    for (int u = 0; u < PF; ++u) {
        if (tb + u < Tc) {
            float4 ev = q[u];
            float e[4] = {ev.x, ev.y, ev.z, ev.w};
            hmm_step(alpha, e, s, valid, lane);
        }
    }

    // final logsumexp over 256 states
    float r = logadd2(logadd2(alpha[0], alpha[1]), logadd2(alpha[2], alpha[3]));
#pragma unroll
    for (int off = 32; off >= 1; off >>= 1) {
        float o = __shfl_xor(r, off, 64);
        r = logadd2(r, o);
    }
    if (lane == 0) out[b] = r;
}

// ---------------- Fused fallback (if workspace too small) ----------------
__global__ __launch_bounds__(64) void fused_scan_kernel(
    const float* __restrict__ lp, const float* __restrict__ lens,
    const int* __restrict__ phns, const float* __restrict__ phn_lens,
    float* __restrict__ out) {
    int b = blockIdx.x;
    int lane = threadIdx.x;
    int Tv = (int)rintf(lens[b] * (float)Tc);
    int Uv = (int)rintf(phn_lens[b] * (float)Uc);
    const float* lpb = lp + (size_t)b * Tc * Vc;

    int col[4];
    float s[4];
    bool valid[4];
#pragma unroll
    for (int c = 0; c < 4; ++c) {
        int i = lane + 64 * c;
        int cc = phns[b * Uc + i];
        if (cc < 0) cc = 0;
        if (cc >= Vc) cc = Vc - 1;
        col[c] = cc;
        valid[c] = (i < Uv);
        s[c] = (i == Uv - 1) ? 0.0f : NLOG2;
    }

    float alpha[4];
#pragma unroll
    for (int c = 0; c < 4; ++c) {
        int i = lane + 64 * c;
        float e = (valid[c] && 0 < Tv) ? lpb[col[c]] : NEG_INF_F;
        alpha[c] = ((i == 0) ? 0.0f : NEG_INF_F) + e;
    }

    const int PF = 8;
    float q[PF][4];
#pragma unroll
    for (int p = 0; p < PF; ++p) {
        int t = 1 + p;
        if (t > Tc - 1) t = Tc - 1;
#pragma unroll
        for (int c = 0; c < 4; ++c)
            q[p][c] = (valid[c] && t < Tv) ? lpb[(size_t)t * Vc + col[c]] : NEG_INF_F;
    }

    int tb;
    for (tb = 1; tb + PF <= Tc; tb += PF) {
#pragma unroll
        for (int u = 0; u < PF; ++u) {
            int t = tb + u;
            float e[4] = {q[u][0], q[u][1], q[u][2], q[u][3]};
            int tn = t + PF;
            if (tn < Tc) {
#pragma unroll
                for (int c = 0; c < 4; ++c)
                    q[u][c] = (valid[c] && tn < Tv) ? lpb[(size_t)tn * Vc + col[c]] : NEG_INF_F;
            }
            hmm_step(alpha, e, s, valid, lane);
        }
    }
#pragma unroll
    for (int u = 0; u < PF; ++u) {
        if (tb + u < Tc) {
            float e[4] = {q[u][0], q[u][1], q[u][2], q[u][3]};
            hmm_step(alpha, e, s, valid, lane);
        }
    }

    float r = logadd2(logadd2(alpha[0], alpha[1]), logadd2(alpha[2], alpha[3]));
#pragma unroll
    for (int off = 32; off >= 1; off >>= 1) {
        float o = __shfl_xor(r, off, 64);
        r = logadd2(r, o);
    }
    if (lane == 0) out[b] = r;
}

extern "C" void kernel_launch(void* const* d_in, const int* in_sizes, int n_in,
                              void* d_out, int out_size, void* d_ws, size_t ws_size,
                              hipStream_t stream) {
    const float* lp = (const float*)d_in[0];
    const float* lens = (const float*)d_in[1];
    const int* phns = (const int*)d_in[2];
    const float* phn_lens = (const float*)d_in[3];
    float* out = (float*)d_out;

    size_t need = (size_t)Bc * Tc * 256 * sizeof(float); // 65.5 MB
    if (ws_size >= need) {
        float* ews = (float*)d_ws;
        const int nchunk = (Tc + 7) / 8; // 125
        gather_kernel<<<Bc * nchunk, 256, 0, stream>>>(lp, lens, phns, phn_lens, ews);
        scan_kernel<<<Bc, 64, 0, stream>>>(ews, lens, phn_lens, out);
    } else {
        fused_scan_kernel<<<Bc, 64, 0, stream>>>(lp, lens, phns, phn_lens, out);
    }
}

// Round 2
// 470.210 us; speedup vs baseline: 1.0605x; 1.0605x over previous
//
#include <hip/hip_runtime.h>
#include <math.h>

// Problem dims (fixed by setup_inputs)
constexpr int Bc = 64;
constexpr int Tc = 1000;
constexpr int Vc = 512;
constexpr int Uc = 256;

#define NEG_INF_F (-100000.0f)
#define NLOG2 (-0.69314718055994531f)

__device__ __forceinline__ float logadd2(float x, float y) {
    float m = fmaxf(x, y);
    float d = fminf(x, y) - m;           // <= 0, may be -inf
    return m + __logf(1.0f + __expf(d)); // expf(-inf) -> 0
}

// One HMM step. Consecutive-state layout: lane holds states i = 4*lane + c.
// Neighbor (i-1) is in-register for c=1..3; only c=0 needs lane-1's alpha[3].
// The cross-lane chain advances one lane per 4 steps -> shfl latency amortized.
__device__ __forceinline__ void hmm_step4(float alpha[4], const float e[4],
                                          const float s[4], const bool valid[4],
                                          int lanem1, bool lane0) {
    float prev3 = __shfl(alpha[3], lanem1, 64);
    float nb0 = lane0 ? -INFINITY : prev3;
    float nb[4] = {nb0, alpha[0], alpha[1], alpha[2]};
    float x[4];
#pragma unroll
    for (int c = 0; c < 4; ++c)
        x[c] = logadd2(s[c] + alpha[c], nb[c] + NLOG2);
#pragma unroll
    for (int c = 0; c < 4; ++c)
        alpha[c] = valid[c] ? (x[c] + e[c]) : NEG_INF_F;
}

// ---------------- Phase 1: gather emissions, LDS-staged ----------------
// ews[b][t][i] = lp[b][t][phns[b][i]] (or NEG_INF), i = state index.
// Each block: one batch b, TCHUNK t-rows. Rows loaded to LDS coalesced,
// gathered from LDS (random banks, cheap), written coalesced.
constexpr int TCHUNK = 8;
__global__ __launch_bounds__(256, 1) void gather_kernel(
    const float* __restrict__ lp, const float* __restrict__ lens,
    const int* __restrict__ phns, const float* __restrict__ phn_lens,
    float* __restrict__ ews) {
    __shared__ float rows[TCHUNK * Vc]; // 16 KB
    const int nchunk = (Tc + TCHUNK - 1) / TCHUNK; // 125
    int b = blockIdx.x / nchunk;
    int tcix = blockIdx.x % nchunk;
    int t0 = tcix * TCHUNK;
    int nt = (t0 + TCHUNK <= Tc) ? TCHUNK : (Tc - t0);
    int tid = threadIdx.x;

    // stage nt rows (nt * 512 floats) into LDS with float4 loads
    const float4* src = (const float4*)(lp + (size_t)b * Tc * Vc + (size_t)t0 * Vc);
    float4* dst = (float4*)rows;
    int n4 = nt * (Vc / 4);
    for (int k = tid; k < n4; k += 256) dst[k] = src[k];

    int Tv = (int)rintf(lens[b] * (float)Tc);
    int Uv = (int)rintf(phn_lens[b] * (float)Uc);
    int col = phns[b * Uc + tid];
    if (col < 0) col = 0;
    if (col >= Vc) col = Vc - 1;
    bool iv = (tid < Uv);
    float* eb = ews + (size_t)b * Tc * 256 + (size_t)t0 * 256;

    __syncthreads();
    for (int tl = 0; tl < nt; ++tl) {
        int t = t0 + tl;
        float e = (iv && t < Tv) ? rows[tl * Vc + col] : NEG_INF_F;
        eb[tl * 256 + tid] = e; // coalesced
    }
}

// ---------------- Phase 2: sequential scan, one wave per batch ----------------
__global__ __launch_bounds__(64, 1) void scan_kernel(
    const float* __restrict__ ews, const float* __restrict__ lens,
    const float* __restrict__ phn_lens, float* __restrict__ out) {
    int b = blockIdx.x;
    int lane = threadIdx.x;
    int lanem1 = (lane + 63) & 63;
    bool lane0 = (lane == 0);
    int Uv = (int)rintf(phn_lens[b] * (float)Uc);

    // lane reads states 4*lane .. 4*lane+3 as one float4; row stride 64 float4s
    const float4* e4 = (const float4*)(ews + (size_t)b * Tc * 256) + lane;

    float s[4];
    bool valid[4];
    float alpha[4];
    float4 e0 = e4[0];
    float e0a[4] = {e0.x, e0.y, e0.z, e0.w};
#pragma unroll
    for (int c = 0; c < 4; ++c) {
        int i = 4 * lane + c;
        valid[c] = (i < Uv);
        s[c] = (i == Uv - 1) ? 0.0f : NLOG2;
        alpha[c] = ((i == 0) ? 0.0f : NEG_INF_F) + e0a[c]; // pi + emiss[0]
    }

    const int PF = 16; // prefetch lead must exceed memory latency / step time
    float4 q[PF];
#pragma unroll
    for (int p = 0; p < PF; ++p) {
        int t = 1 + p;
        if (t > Tc - 1) t = Tc - 1;
        q[p] = e4[(size_t)t * 64];
    }

    int tb;
    for (tb = 1; tb + PF <= Tc; tb += PF) {
#pragma unroll
        for (int u = 0; u < PF; ++u) {
            int t = tb + u;
            float4 ev = q[u];
            int tn = t + PF;
            if (tn < Tc) q[u] = e4[(size_t)tn * 64]; // prefetch PF steps ahead
            float e[4] = {ev.x, ev.y, ev.z, ev.w};
            hmm_step4(alpha, e, s, valid, lanem1, lane0);
        }
    }
    // tail (< PF steps), values already prefetched in q[0..]
#pragma unroll
    for (int u = 0; u < PF; ++u) {
        if (tb + u < Tc) {
            float4 ev = q[u];
            float e[4] = {ev.x, ev.y, ev.z, ev.w};
            hmm_step4(alpha, e, s, valid, lanem1, lane0);
        }
    }

    // final logsumexp over 256 states
    float r = logadd2(logadd2(alpha[0], alpha[1]), logadd2(alpha[2], alpha[3]));
#pragma unroll
    for (int off = 32; off >= 1; off >>= 1) {
        float o = __shfl_xor(r, off, 64);
        r = logadd2(r, o);
    }
    if (lane == 0) out[b] = r;
}

// ---------------- Fused fallback (if workspace too small) ----------------
__global__ __launch_bounds__(64, 1) void fused_scan_kernel(
    const float* __restrict__ lp, const float* __restrict__ lens,
    const int* __restrict__ phns, const float* __restrict__ phn_lens,
    float* __restrict__ out) {
    int b = blockIdx.x;
    int lane = threadIdx.x;
    int lanem1 = (lane + 63) & 63;
    bool lane0 = (lane == 0);
    int Tv = (int)rintf(lens[b] * (float)Tc);
    int Uv = (int)rintf(phn_lens[b] * (float)Uc);
    const float* lpb = lp + (size_t)b * Tc * Vc;

    int col[4];
    float s[4];
    bool valid[4];
#pragma unroll
    for (int c = 0; c < 4; ++c) {
        int i = 4 * lane + c;
        int cc = phns[b * Uc + i];
        if (cc < 0) cc = 0;
        if (cc >= Vc) cc = Vc - 1;
        col[c] = cc;
        valid[c] = (i < Uv);
        s[c] = (i == Uv - 1) ? 0.0f : NLOG2;
    }

    float alpha[4];
#pragma unroll
    for (int c = 0; c < 4; ++c) {
        int i = 4 * lane + c;
        float e = (valid[c] && 0 < Tv) ? lpb[col[c]] : NEG_INF_F;
        alpha[c] = ((i == 0) ? 0.0f : NEG_INF_F) + e;
    }

    const int PF = 8;
    float q[PF][4];
#pragma unroll
    for (int p = 0; p < PF; ++p) {
        int t = 1 + p;
        if (t > Tc - 1) t = Tc - 1;
#pragma unroll
        for (int c = 0; c < 4; ++c)
            q[p][c] = (valid[c] && t < Tv) ? lpb[(size_t)t * Vc + col[c]] : NEG_INF_F;
    }

    int tb;
    for (tb = 1; tb + PF <= Tc; tb += PF) {
#pragma unroll
        for (int u = 0; u < PF; ++u) {
            int t = tb + u;
            float e[4] = {q[u][0], q[u][1], q[u][2], q[u][3]};
            int tn = t + PF;
            if (tn < Tc) {
#pragma unroll
                for (int c = 0; c < 4; ++c)
                    q[u][c] = (valid[c] && tn < Tv) ? lpb[(size_t)tn * Vc + col[c]] : NEG_INF_F;
            }
            hmm_step4(alpha, e, s, valid, lanem1, lane0);
        }
    }
#pragma unroll
    for (int u = 0; u < PF; ++u) {
        if (tb + u < Tc) {
            float e[4] = {q[u][0], q[u][1], q[u][2], q[u][3]};
            hmm_step4(alpha, e, s, valid, lanem1, lane0);
        }
    }

    float r = logadd2(logadd2(alpha[0], alpha[1]), logadd2(alpha[2], alpha[3]));
#pragma unroll
    for (int off = 32; off >= 1; off >>= 1) {
        float o = __shfl_xor(r, off, 64);
        r = logadd2(r, o);
    }
    if (lane == 0) out[b] = r;
}

extern "C" void kernel_launch(void* const* d_in, const int* in_sizes, int n_in,
                              void* d_out, int out_size, void* d_ws, size_t ws_size,
                              hipStream_t stream) {
    const float* lp = (const float*)d_in[0];
    const float* lens = (const float*)d_in[1];
    const int* phns = (const int*)d_in[2];
    const float* phn_lens = (const float*)d_in[3];
    float* out = (float*)d_out;

    size_t need = (size_t)Bc * Tc * 256 * sizeof(float); // 65.5 MB
    if (ws_size >= need) {
        float* ews = (float*)d_ws;
        const int nchunk = (Tc + TCHUNK - 1) / TCHUNK; // 125
        gather_kernel<<<Bc * nchunk, 256, 0, stream>>>(lp, lens, phns, phn_lens, ews);
        scan_kernel<<<Bc, 64, 0, stream>>>(ews, lens, phn_lens, out);
    } else {
        fused_scan_kernel<<<Bc, 64, 0, stream>>>(lp, lens, phns, phn_lens, out);
    }
}

// Round 3
// 386.915 us; speedup vs baseline: 1.2888x; 1.2153x over previous
//
#include <hip/hip_runtime.h>
#include <math.h>

// Problem dims (fixed by setup_inputs)
constexpr int Bc = 64;
constexpr int Tc = 1000;
constexpr int Vc = 512;
constexpr int Uc = 256;
constexpr int CH = 50;          // t-rows per LDS chunk (2*CH KB LDS total)
constexpr int NCH = Tc / CH;    // 20 chunks exactly
constexpr int PW = 7;           // producer waves (waves 1..7); wave 0 = consumer

#define NEG_INF_F (-100000.0f)
#define NLOG2 (-0.69314718055994531f)

__device__ __forceinline__ float logadd2(float x, float y) {
    float m = fmaxf(x, y);
    float d = fminf(x, y) - m;           // <= 0, may be -inf
    return m + __logf(1.0f + __expf(d)); // expf(-inf) -> 0
}

// One HMM step. Lane holds states i = 4*lane + c (consecutive).
// Neighbor (i-1) in-register for c=1..3; only c=0 crosses lanes (1 shfl/step,
// and the cross-lane dependency chain advances one lane per 4 steps).
__device__ __forceinline__ void hmm_step4(float alpha[4], const float4 ev,
                                          const float s[4], const bool valid[4],
                                          int lanem1, bool lane0) {
    float prev3 = __shfl(alpha[3], lanem1, 64);
    float nb0 = lane0 ? -INFINITY : prev3;
    float e[4] = {ev.x, ev.y, ev.z, ev.w};
    float nb[4] = {nb0, alpha[0], alpha[1], alpha[2]};
    float x[4];
#pragma unroll
    for (int c = 0; c < 4; ++c)
        x[c] = logadd2(s[c] + alpha[c], nb[c] + NLOG2);
#pragma unroll
    for (int c = 0; c < 4; ++c)
        alpha[c] = valid[c] ? (x[c] + e[c]) : NEG_INF_F;
}

__global__ __launch_bounds__(512, 1) void fused_hmm_kernel(
    const float* __restrict__ lp, const float* __restrict__ lens,
    const int* __restrict__ phns, const float* __restrict__ phn_lens,
    float* __restrict__ out) {
    __shared__ float ebuf[2][CH][Uc]; // 100 KB double buffer of emission rows
    int b = blockIdx.x;
    int tid = threadIdx.x;
    int wave = tid >> 6;
    int lane = tid & 63;
    int lanem1 = (lane + 63) & 63;
    bool lane0 = (lane == 0);
    int Tv = (int)rintf(lens[b] * (float)Tc);
    int Uv = (int)rintf(phn_lens[b] * (float)Uc);

    // ---- per-role persistent state (declared for all; cheap) ----
    // producer: clamped phoneme columns + validity for states 4*lane+c
    int col[4];
    bool pv[4];
    const float* lpb = lp + (size_t)b * Tc * Vc;
    // consumer: alpha and per-state constants
    float alpha[4], s[4];
    bool valid[4];

    if (wave > 0) {
        int4 cc = *(const int4*)(phns + (size_t)b * Uc + 4 * lane);
        int c4[4] = {cc.x, cc.y, cc.z, cc.w};
#pragma unroll
        for (int c = 0; c < 4; ++c) {
            int v = c4[c];
            v = v < 0 ? 0 : (v > Vc - 1 ? Vc - 1 : v);
            col[c] = v;
            pv[c] = (4 * lane + c) < Uv;
        }
    } else {
#pragma unroll
        for (int c = 0; c < 4; ++c) {
            int i = 4 * lane + c;
            valid[c] = (i < Uv);
            s[c] = (i == Uv - 1) ? 0.0f : NLOG2;
            alpha[c] = NEG_INF_F; // set properly from chunk 0 row 0
        }
    }

    // producer: fill chunk k into ebuf[k&1]; two rows per iteration for MLP
    auto fill = [&](int k) {
        float* dst = &ebuf[k & 1][0][0];
        int tb = k * CH;
        int rb = wave - 1;
        for (int r0 = rb; r0 < CH; r0 += 2 * PW) {
            int r1 = r0 + PW;
            bool h1 = (r1 < CH);
            int t0 = tb + r0, t1 = tb + r1;
            float a0[4], a1[4];
#pragma unroll
            for (int c = 0; c < 4; ++c)
                a0[c] = (pv[c] && t0 < Tv) ? lpb[(size_t)t0 * Vc + col[c]] : NEG_INF_F;
#pragma unroll
            for (int c = 0; c < 4; ++c)
                a1[c] = (h1 && pv[c] && t1 < Tv) ? lpb[(size_t)t1 * Vc + col[c]] : NEG_INF_F;
            *(float4*)(dst + r0 * Uc + 4 * lane) = make_float4(a0[0], a0[1], a0[2], a0[3]);
            if (h1)
                *(float4*)(dst + r1 * Uc + 4 * lane) = make_float4(a1[0], a1[1], a1[2], a1[3]);
        }
    };

    // consumer: run scan over chunk k from LDS with a 4-deep register pipeline
    auto consume = [&](int k) {
        const float4* base = (const float4*)&ebuf[k & 1][0][0] + lane; // row stride 64
        int r = 0;
        if (k == 0) {
            float4 e0 = base[0];
            float e0a[4] = {e0.x, e0.y, e0.z, e0.w};
#pragma unroll
            for (int c = 0; c < 4; ++c)
                alpha[c] = ((4 * lane + c == 0) ? 0.0f : NEG_INF_F) + e0a[c]; // pi + emiss[0]
            r = 1;
        }
        float4 q0, q1, q2, q3;
        if (r + 0 < CH) q0 = base[(r + 0) * 64];
        if (r + 1 < CH) q1 = base[(r + 1) * 64];
        if (r + 2 < CH) q2 = base[(r + 2) * 64];
        if (r + 3 < CH) q3 = base[(r + 3) * 64];
        while (r + 4 <= CH) {
            float4 e0 = q0, e1 = q1, e2 = q2, e3 = q3;
            if (r + 4 < CH) q0 = base[(r + 4) * 64];
            if (r + 5 < CH) q1 = base[(r + 5) * 64];
            if (r + 6 < CH) q2 = base[(r + 6) * 64];
            if (r + 7 < CH) q3 = base[(r + 7) * 64];
            hmm_step4(alpha, e0, s, valid, lanem1, lane0);
            hmm_step4(alpha, e1, s, valid, lanem1, lane0);
            hmm_step4(alpha, e2, s, valid, lanem1, lane0);
            hmm_step4(alpha, e3, s, valid, lanem1, lane0);
            r += 4;
        }
        if (r + 0 < CH) hmm_step4(alpha, q0, s, valid, lanem1, lane0);
        if (r + 1 < CH) hmm_step4(alpha, q1, s, valid, lanem1, lane0);
        if (r + 2 < CH) hmm_step4(alpha, q2, s, valid, lanem1, lane0);
    };

    // ---- pipeline: barriers OUTSIDE the role branch (uniform count) ----
    if (wave > 0) fill(0);
    __syncthreads();
    for (int k = 0; k < NCH; ++k) {
        if (wave > 0) {
            if (k + 1 < NCH) fill(k + 1);
        } else {
            consume(k);
        }
        __syncthreads();
    }

    if (wave == 0) {
        float r = logadd2(logadd2(alpha[0], alpha[1]), logadd2(alpha[2], alpha[3]));
#pragma unroll
        for (int off = 32; off >= 1; off >>= 1) {
            float o = __shfl_xor(r, off, 64);
            r = logadd2(r, o);
        }
        if (lane == 0) out[b] = r;
    }
}

extern "C" void kernel_launch(void* const* d_in, const int* in_sizes, int n_in,
                              void* d_out, int out_size, void* d_ws, size_t ws_size,
                              hipStream_t stream) {
    const float* lp = (const float*)d_in[0];
    const float* lens = (const float*)d_in[1];
    const int* phns = (const int*)d_in[2];
    const float* phn_lens = (const float*)d_in[3];
    float* out = (float*)d_out;
    (void)d_ws; (void)ws_size; (void)in_sizes; (void)n_in; (void)out_size;

    fused_hmm_kernel<<<Bc, 512, 0, stream>>>(lp, lens, phns, phn_lens, out);
}

// Round 5
// 286.486 us; speedup vs baseline: 1.7406x; 1.3506x over previous
//
#include <hip/hip_runtime.h>
#include <math.h>

// Problem dims (fixed by setup_inputs)
constexpr int Bc = 64;
constexpr int Tc = 1000;
constexpr int Vc = 512;
constexpr int Uc = 256;
constexpr int CH = 50;        // t-rows per LDS chunk
constexpr int NCH = Tc / CH;  // 20 chunks
constexpr int PW = 7;         // producer waves (waves 1..7); wave 0 = consumer

#define NEG_INF_F (-100000.0f)
#define LOG2E_F 1.44269504088896340736f
#define LN2_F 0.69314718055994530942f
#define DEAD_F (-1.0e9f)

// raw v_exp_f32 (2^x) / v_log_f32 (log2 x)
__device__ __forceinline__ float fexp2(float x) {
#if __has_builtin(__builtin_amdgcn_exp2f)
    return __builtin_amdgcn_exp2f(x);
#else
    return __expf(x * LN2_F);
#endif
}
__device__ __forceinline__ float flog2(float x) {
#if __has_builtin(__builtin_amdgcn_logf)
    return __builtin_amdgcn_logf(x);
#else
    return __logf(x) * LOG2E_F;
#endif
}

// log2-domain logadd: log2(2^x + 2^y)
__device__ __forceinline__ float l2add(float x, float y) {
    float m = fmaxf(x, y);
    float p = fexp2(-fabsf(x - y)); // v_exp_f32 with -|.| source modifiers
    return m + flog2(1.0f + p);     // v_log_f32
}

// One HMM step in shifted log2 domain:
//   r_i(t) = log2add(r_i(t-1), r_{i-1}(t-1)) + E2_i(t)
// (transition constants pre-folded into E2 by the producer; shift d=-1 on
// non-last states, 0 on the last state makes the step uniform).
// Lane holds states i = 4*lane + c; only c=0 crosses lanes, and that link is
// on the dependency chain only once per 4 steps (slack >> shfl latency).
__device__ __forceinline__ void hmm_step(float rr[4], const float4 ev, float pen) {
    float nb0 = __shfl_up(rr[3], 1, 64) + pen; // lane0: own value - 1e9 ~= -inf
    float e[4] = {ev.x, ev.y, ev.z, ev.w};
    float nb[4] = {nb0, rr[0], rr[1], rr[2]};
#pragma unroll
    for (int c = 0; c < 4; ++c) {
        float x = rr[c], y = nb[c];
        float m = fmaxf(x, y);
        float p = fexp2(-fabsf(x - y));
        rr[c] = m + flog2(1.0f + p) + e[c];
    }
}

__global__ __launch_bounds__(512, 1) void fused_hmm_kernel(
    const float* __restrict__ lp, const float* __restrict__ lens,
    const int* __restrict__ phns, const float* __restrict__ phn_lens,
    float* __restrict__ out) {
    __shared__ float ebuf[2][CH][Uc];  // 100 KB: gathered emissions (E2 form)
    __shared__ float stage[PW][2][Vc]; // 28 KB: per-producer-wave row staging
    const int b = blockIdx.x;
    const int tid = threadIdx.x;
    const int wave = tid >> 6;
    const int lane = tid & 63;
    const int Tv = (int)rintf(lens[b] * (float)Tc);
    const int Uv = (int)rintf(phn_lens[b] * (float)Uc);
    const float* lpb = lp + (size_t)b * Tc * Vc;

    // ---------------- producer state ----------------
    int col[4];
    float off[4];
    bool pv[4];
    float* st0 = nullptr;
    float* st1 = nullptr;
    // ---------------- consumer state ----------------
    float rr[4];
    const float pen = (lane == 0) ? DEAD_F : 0.0f;

    if (wave > 0) {
        const int widx = wave - 1;
        int4 cc = *(const int4*)(phns + (size_t)b * Uc + 4 * lane);
        int c4[4] = {cc.x, cc.y, cc.z, cc.w};
#pragma unroll
        for (int c = 0; c < 4; ++c) {
            int v = c4[c];
            v = v < 0 ? 0 : (v > Vc - 1 ? Vc - 1 : v);
            col[c] = v;
            int i = 4 * lane + c;
            pv[c] = (i < Uv);
            off[c] = (i == Uv - 1) ? 0.0f : -1.0f; // -1 = transition const (log2 units)
        }
        st0 = &stage[widx][0][0];
        st1 = &stage[widx][1][0];
    }

    // producer: gather chunk k into ebuf[k&1] via coalesced load + LDS stage.
    // Rows round-robin across the 7 producer waves; stage slots are per-wave
    // private so no barrier is needed for the stage round-trip (same-wave DS
    // ops execute in order). One-row-ahead global prefetch.
    auto fill = [&](int k) {
        float* dst = &ebuf[k & 1][0][0];
        const int tb = k * CH;
        int r = wave - 1;
        float4 v0a, v1a;
        {
            int t = tb + r;
            const float4* rp = (const float4*)(lpb + (size_t)t * Vc);
            if (r < CH && t < Tv) { v0a = rp[lane]; v1a = rp[64 + lane]; }
        }
        int slot = 0;
        while (r < CH) {
            const int t = tb + r;
            const int rn = r + PW;
            float4 v0b, v1b;
            if (rn < CH) {
                int tn = tb + rn;
                if (tn < Tv) {
                    const float4* rp = (const float4*)(lpb + (size_t)tn * Vc);
                    v0b = rp[lane];
                    v1b = rp[64 + lane];
                }
            }
            float* st = slot ? st1 : st0;
            const bool tv = (t < Tv);
            if (tv) {
                ((float4*)st)[lane] = v0a;      // coalesced b128 LDS writes
                ((float4*)st)[64 + lane] = v1a;
            }
            float ev[4];
#pragma unroll
            for (int c = 0; c < 4; ++c) {
                float e = st[col[c]]; // random-bank ds_read_b32 (cheap)
                ev[c] = (pv[c] && tv) ? fmaf(e, LOG2E_F, off[c])
                                      : (NEG_INF_F * LOG2E_F + off[c]);
            }
            *(float4*)(dst + r * Uc + 4 * lane) = make_float4(ev[0], ev[1], ev[2], ev[3]);
            v0a = v0b; v1a = v1b;
            slot ^= 1;
            r = rn;
        }
    };

    // consumer: scan chunk k from LDS with a 4-deep register pipeline
    auto consume = [&](int k) {
        const float4* base = (const float4*)&ebuf[k & 1][0][0] + lane; // row stride 64
        int r = 0;
        if (k == 0) {
            float4 e0 = base[0];
            float ea[4] = {e0.x, e0.y, e0.z, e0.w};
#pragma unroll
            for (int c = 0; c < 4; ++c)
                rr[c] = ((4 * lane + c == 0) ? 0.0f : DEAD_F) + ea[c]; // pi + E2(0)
            r = 1;
        }
        float4 q0, q1, q2, q3;
        if (r + 0 < CH) q0 = base[(r + 0) * 64];
        if (r + 1 < CH) q1 = base[(r + 1) * 64];
        if (r + 2 < CH) q2 = base[(r + 2) * 64];
        if (r + 3 < CH) q3 = base[(r + 3) * 64];
        while (r + 4 <= CH) {
            float4 e0 = q0, e1 = q1, e2 = q2, e3 = q3;
            if (r + 4 < CH) q0 = base[(r + 4) * 64];
            if (r + 5 < CH) q1 = base[(r + 5) * 64];
            if (r + 6 < CH) q2 = base[(r + 6) * 64];
            if (r + 7 < CH) q3 = base[(r + 7) * 64];
            hmm_step(rr, e0, pen);
            hmm_step(rr, e1, pen);
            hmm_step(rr, e2, pen);
            hmm_step(rr, e3, pen);
            r += 4;
        }
        if (r + 0 < CH) hmm_step(rr, q0, pen);
        if (r + 1 < CH) hmm_step(rr, q1, pen);
        if (r + 2 < CH) hmm_step(rr, q2, pen);
    };

    // ---- pipeline: barriers OUTSIDE the role branch (uniform count) ----
    if (wave > 0) fill(0);
    __syncthreads();
    for (int k = 0; k < NCH; ++k) {
        if (wave > 0) {
            if (k + 1 < NCH) fill(k + 1);
        } else {
            consume(k);
        }
        __syncthreads();
    }

    if (wave == 0) {
        // undo the shift (+1 on non-last states), then logsumexp over states
        float a[4];
#pragma unroll
        for (int c = 0; c < 4; ++c)
            a[c] = rr[c] + ((4 * lane + c == Uv - 1) ? 0.0f : 1.0f);
        float r2 = l2add(l2add(a[0], a[1]), l2add(a[2], a[3]));
#pragma unroll
        for (int o = 32; o >= 1; o >>= 1) {
            float t = __shfl_xor(r2, o, 64);
            r2 = l2add(r2, t);
        }
        if (lane == 0) out[b] = r2 * LN2_F; // back to nats
    }
}

extern "C" void kernel_launch(void* const* d_in, const int* in_sizes, int n_in,
                              void* d_out, int out_size, void* d_ws, size_t ws_size,
                              hipStream_t stream) {
    const float* lp = (const float*)d_in[0];
    const float* lens = (const float*)d_in[1];
    const int* phns = (const int*)d_in[2];
    const float* phn_lens = (const float*)d_in[3];
    float* out = (float*)d_out;
    (void)d_ws; (void)ws_size; (void)in_sizes; (void)n_in; (void)out_size;

    fused_hmm_kernel<<<Bc, 512, 0, stream>>>(lp, lens, phns, phn_lens, out);
}